// Round 1
// baseline (278.052 us; speedup 1.0000x reference)
//
#include <hip/hip_runtime.h>

// DCNv1 forward, fused bilinear-im2col + GEMM, fp32 VALU.
// B=8, C=128, H=W=64, O=128, K=3x3, stride=1, pad=1, dil=1 -> Ho=Wo=64.
// Grid: 512 blocks = (b, ho). Block: 256 threads.
// Per block: M=64 (wo) x N=128 (o), K_red = 1152 in 16 chunks of 72 (8 ch x 9 taps).
// Thread tile: 8 wo x 4 o (32 fp32 acc). LDS: samples SoA + col[72][64] + w[72][132].

#define BB 8
#define CC_TOT 128
#define HH 64
#define WW 64
#define OO 128
#define KK 9
#define HOo 64
#define WOo 64
#define CCHUNK 8
#define RR (CCHUNK * KK)   // 72
#define WSTRIDE 132        // 128 + 4 pad (keeps 16B alignment, breaks bank stride)

__global__ __launch_bounds__(256, 2)
void dcn_fused_kernel(const float* __restrict__ x,
                      const float* __restrict__ offset,
                      const float* __restrict__ wgt,
                      const float* __restrict__ bias,
                      float* __restrict__ out) {
    __shared__ __align__(16) float sw00[KK * WOo];
    __shared__ __align__(16) float sw01[KK * WOo];
    __shared__ __align__(16) float sw10[KK * WOo];
    __shared__ __align__(16) float sw11[KK * WOo];
    __shared__ __align__(16) int   sa00[KK * WOo];
    __shared__ __align__(16) int   sa01[KK * WOo];
    __shared__ __align__(16) int   sa10[KK * WOo];
    __shared__ __align__(16) int   sa11[KK * WOo];
    __shared__ __align__(16) float col_lds[RR * WOo];      // 18.4 KB
    __shared__ __align__(16) float w_lds[RR * WSTRIDE];    // 38.0 KB

    const int t  = threadIdx.x;
    const int b  = blockIdx.x >> 6;
    const int ho = blockIdx.x & 63;

    // ---- Phase A: sampling records for this (b, ho) row: 9 taps x 64 wo ----
    for (int s = t; s < KK * WOo; s += 256) {
        const int k  = s >> 6;
        const int wo = s & 63;
        const int ki = k / 3;
        const int kj = k - ki * 3;
        const float dy = offset[(((size_t)b * 18 + 2 * k    ) * 64 + ho) * 64 + wo];
        const float dx = offset[(((size_t)b * 18 + 2 * k + 1) * 64 + ho) * 64 + wo];
        const float py = (float)(ho - 1 + ki) + dy;
        const float px = (float)(wo - 1 + kj) + dx;
        const float y0f = floorf(py);
        const float x0f = floorf(px);
        const float ly = py - y0f;
        const float lx = px - x0f;
        const int y0 = (int)y0f, x0 = (int)x0f;
        const int y1 = y0 + 1,   x1 = x0 + 1;
        const bool vy0 = (y0 >= 0) && (y0 < HH);
        const bool vy1 = (y1 >= 0) && (y1 < HH);
        const bool vx0 = (x0 >= 0) && (x0 < WW);
        const bool vx1 = (x1 >= 0) && (x1 < WW);
        const int cy0 = min(max(y0, 0), HH - 1);
        const int cy1 = min(max(y1, 0), HH - 1);
        const int cx0 = min(max(x0, 0), WW - 1);
        const int cx1 = min(max(x1, 0), WW - 1);
        sw00[s] = (vy0 && vx0) ? (1.f - ly) * (1.f - lx) : 0.f;
        sw01[s] = (vy0 && vx1) ? (1.f - ly) * lx         : 0.f;
        sw10[s] = (vy1 && vx0) ? ly * (1.f - lx)         : 0.f;
        sw11[s] = (vy1 && vx1) ? ly * lx                 : 0.f;
        sa00[s] = cy0 * WW + cx0;
        sa01[s] = cy0 * WW + cx1;
        sa10[s] = cy1 * WW + cx0;
        sa11[s] = cy1 * WW + cx1;
    }

    float acc[8][4];
#pragma unroll
    for (int i = 0; i < 8; ++i)
#pragma unroll
        for (int j = 0; j < 4; ++j) acc[i][j] = 0.f;

    const int wg = t & 7;   // wo in [wg*8, wg*8+8)
    const int og = t >> 3;  // o  in [og*4, og*4+4)

    __syncthreads();

    for (int c0 = 0; c0 < CC_TOT; c0 += CCHUNK) {
        // ---- stage weights: w_lds[r][o] <- wgt[o][c0*9 + r] (contiguous runs of 72) ----
        for (int i = t; i < RR * OO; i += 256) {
            const int o = i / RR;
            const int r = i - o * RR;
            w_lds[r * WSTRIDE + o] = wgt[(size_t)o * (CC_TOT * KK) + c0 * KK + r];
        }
        // ---- stage cols: col_lds[r][wo] = bilinear sample of channel c0 + r/9, tap r%9 ----
        for (int i = t; i < RR * WOo; i += 256) {
            const int r  = i >> 6;
            const int wo = i & 63;
            const int cl = r / 9;
            const int k  = r - cl * 9;
            const int s  = (k << 6) + wo;
            const float* xb = x + ((size_t)(b * CC_TOT + c0 + cl) << 12);
            col_lds[i] = sw00[s] * xb[sa00[s]] + sw01[s] * xb[sa01[s]]
                       + sw10[s] * xb[sa10[s]] + sw11[s] * xb[sa11[s]];
        }
        __syncthreads();

        // ---- register-tile GEMM over this chunk ----
#pragma unroll 4
        for (int r = 0; r < RR; ++r) {
            const float4 ca = *reinterpret_cast<const float4*>(&col_lds[(r << 6) + wg * 8]);
            const float4 cb = *reinterpret_cast<const float4*>(&col_lds[(r << 6) + wg * 8 + 4]);
            const float4 wv = *reinterpret_cast<const float4*>(&w_lds[r * WSTRIDE + og * 4]);
            const float cv[8] = {ca.x, ca.y, ca.z, ca.w, cb.x, cb.y, cb.z, cb.w};
            const float wvv[4] = {wv.x, wv.y, wv.z, wv.w};
#pragma unroll
            for (int i = 0; i < 8; ++i)
#pragma unroll
                for (int j = 0; j < 4; ++j)
                    acc[i][j] += cv[i] * wvv[j];
        }
        __syncthreads();
    }

    // ---- epilogue: out[b][o][ho][wo] = acc + bias[o] ----
#pragma unroll
    for (int j = 0; j < 4; ++j) {
        const int o = og * 4 + j;
        const float bv = bias[o];
        float* op = out + (((size_t)(b * OO + o) * HOo + ho) << 6) + wg * 8;
        float4 v0 = {acc[0][j] + bv, acc[1][j] + bv, acc[2][j] + bv, acc[3][j] + bv};
        float4 v1 = {acc[4][j] + bv, acc[5][j] + bv, acc[6][j] + bv, acc[7][j] + bv};
        *reinterpret_cast<float4*>(op)     = v0;
        *reinterpret_cast<float4*>(op + 4) = v1;
    }
}

extern "C" void kernel_launch(void* const* d_in, const int* in_sizes, int n_in,
                              void* d_out, int out_size, void* d_ws, size_t ws_size,
                              hipStream_t stream) {
    const float* x      = (const float*)d_in[0];
    const float* offset = (const float*)d_in[1];
    const float* wgt    = (const float*)d_in[2];
    const float* bias   = (const float*)d_in[3];
    float* out = (float*)d_out;

    dim3 grid(BB * HOo);   // 512 blocks: (b, ho)
    dim3 block(256);
    hipLaunchKernelGGL(dcn_fused_kernel, grid, block, 0, stream,
                       x, offset, wgt, bias, out);
}

// Round 2
// 134.298 us; speedup vs baseline: 2.0704x; 2.0704x over previous
//
#include <hip/hip_runtime.h>

// DCNv1 forward on MI355X, bf16 MFMA path.
// B=8, C=128, H=W=64, O=128, 3x3, stride=1, pad=1 -> Ho=Wo=64.
//
// Pass 1: x[B][C][H][W] f32 -> x_t[B][H][W][C] bf16 (channels contiguous)  [d_ws]
// Pass 2: wgt[O][C][3][3] f32 -> w_t[O][tap][C] bf16                        [d_ws]
// Pass 3: fused bilinear-im2col (A-frags built in registers from coalesced
//         16B loads of x_t) + MFMA GEMM.  Block=(b,ho): M=64(wo) x N=128(o),
//         K=1152 ordered tap-major (chunk = one tap = 128 c).
//         Wave w owns m-tile w (16 wo) x all 128 o: 8 MFMA tiles, 32 acc VGPRs.

#define BB 8
#define CC 128
#define HH 64
#define WW 64
#define OO 128
#define KTAPS 9
#define WLDS_STRIDE 136   // 128 bf16 + 8 pad (272 B rows, 16B-aligned, conflict-free)

typedef __attribute__((ext_vector_type(8))) short bf16x8;
typedef __attribute__((ext_vector_type(4))) float f32x4;

__device__ __forceinline__ unsigned short f2bf(float f) {
    unsigned u = __float_as_uint(f);
    u += 0x7FFFu + ((u >> 16) & 1u);   // RNE
    return (unsigned short)(u >> 16);
}
__device__ __forceinline__ float bf2f(unsigned u16) {
    return __uint_as_float(u16 << 16);
}

// ---------------- Pass 1: x -> x_t bf16 NHWC ----------------
__global__ __launch_bounds__(256)
void transpose_x_kernel(const float* __restrict__ x, unsigned short* __restrict__ xt) {
    __shared__ float tile[WW * 129];               // [w][c], stride 129 dwords
    const int b = blockIdx.x >> 6;
    const int h = blockIdx.x & 63;
    const float* src = x + ((size_t)b * CC * HH + h) * WW;
    for (int i = threadIdx.x; i < CC * WW; i += 256) {
        const int c = i >> 6;
        const int w = i & 63;
        tile[w * 129 + c] = src[(size_t)c * (HH * WW) + w];
    }
    __syncthreads();
    unsigned short* dst = xt + ((size_t)b * HH + h) * WW * CC;
    for (int i = threadIdx.x; i < (CC / 2) * WW; i += 256) {
        const int w  = i >> 6;
        const int cp = i & 63;
        const float f0 = tile[w * 129 + 2 * cp];
        const float f1 = tile[w * 129 + 2 * cp + 1];
        const unsigned pack = (unsigned)f2bf(f0) | ((unsigned)f2bf(f1) << 16);
        *reinterpret_cast<unsigned*>(&dst[(size_t)w * CC + 2 * cp]) = pack;
    }
}

// ---------------- Pass 2: wgt -> w_t bf16 [o][tap][c] ----------------
__global__ __launch_bounds__(256)
void transpose_w_kernel(const float* __restrict__ wgt, unsigned short* __restrict__ wt) {
    const int idx = blockIdx.x * 256 + threadIdx.x;
    if (idx >= OO * CC * KTAPS) return;
    const int o   = idx / (CC * KTAPS);
    const int r   = idx - o * (CC * KTAPS);
    const int c   = r / KTAPS;
    const int tap = r - c * KTAPS;
    wt[((size_t)o * KTAPS + tap) * CC + c] = f2bf(wgt[idx]);
}

// ---------------- Pass 3: fused DCN MFMA ----------------
__global__ __launch_bounds__(256, 2)
void dcn_mfma_kernel(const unsigned short* __restrict__ xt,
                     const unsigned short* __restrict__ wt,
                     const float* __restrict__ offset,
                     const float* __restrict__ bias,
                     float* __restrict__ out) {
    __shared__ __align__(16) int4   sA[KTAPS * WW];    // 4 corner byte-offsets per (tap,wo)
    __shared__ __align__(16) float4 sWt[KTAPS * WW];   // 4 bilinear weights (0 if OOB)
    __shared__ __align__(16) unsigned short wlds[OO * WLDS_STRIDE];  // 34.8 KB

    const int t  = threadIdx.x;
    const int b  = blockIdx.x >> 6;
    const int ho = blockIdx.x & 63;

    // ---- sampling records for this (b,ho): 9 taps x 64 wo ----
    for (int s = t; s < KTAPS * WW; s += 256) {
        const int k  = s >> 6;           // tap
        const int wo = s & 63;
        const int ki = k / 3;
        const int kj = k - ki * 3;
        const float dy = offset[(((size_t)b * 18 + 2 * k    ) * 64 + ho) * 64 + wo];
        const float dx = offset[(((size_t)b * 18 + 2 * k + 1) * 64 + ho) * 64 + wo];
        const float py = (float)(ho - 1 + ki) + dy;
        const float px = (float)(wo - 1 + kj) + dx;
        const float y0f = floorf(py);
        const float x0f = floorf(px);
        const float ly = py - y0f;
        const float lx = px - x0f;
        const int y0 = (int)y0f, x0 = (int)x0f;
        const int y1 = y0 + 1,   x1 = x0 + 1;
        const bool vy0 = (y0 >= 0) && (y0 < HH);
        const bool vy1 = (y1 >= 0) && (y1 < HH);
        const bool vx0 = (x0 >= 0) && (x0 < WW);
        const bool vx1 = (x1 >= 0) && (x1 < WW);
        const int cy0 = min(max(y0, 0), HH - 1);
        const int cy1 = min(max(y1, 0), HH - 1);
        const int cx0 = min(max(x0, 0), WW - 1);
        const int cx1 = min(max(x1, 0), WW - 1);
        float4 w4;
        w4.x = (vy0 && vx0) ? (1.f - ly) * (1.f - lx) : 0.f;
        w4.y = (vy0 && vx1) ? (1.f - ly) * lx         : 0.f;
        w4.z = (vy1 && vx0) ? ly * (1.f - lx)         : 0.f;
        w4.w = (vy1 && vx1) ? ly * lx                 : 0.f;
        sWt[s] = w4;
        // byte offsets into x_t[b]: ((y*W + x)*C)*2
        sA[s] = make_int4(((cy0 * WW + cx0) * CC) * 2, ((cy0 * WW + cx1) * CC) * 2,
                          ((cy1 * WW + cx0) * CC) * 2, ((cy1 * WW + cx1) * CC) * 2);
    }

    f32x4 acc[8];
#pragma unroll
    for (int nt = 0; nt < 8; ++nt) acc[nt] = (f32x4){0.f, 0.f, 0.f, 0.f};

    const int lane = t & 63;
    const int wave = t >> 6;     // m-tile index (16 wo per wave)
    const int lm   = lane & 15;  // m within A-tile / n within B-tile
    const int quad = lane >> 4;  // k-group
    const char* xb = (const char*)(xt + (size_t)b * HH * WW * CC);

    __syncthreads();

    for (int tap = 0; tap < KTAPS; ++tap) {
        // ---- stage W for this tap: wlds[o][c] (bf16, padded rows) ----
        {
            const int seg  = t & 15;
            const int orow = t >> 4;
#pragma unroll
            for (int i = 0; i < 8; ++i) {
                const int o = orow + i * 16;
                const uint4 v = *reinterpret_cast<const uint4*>(
                    wt + ((size_t)o * KTAPS + tap) * CC + seg * 8);
                *reinterpret_cast<uint4*>(&wlds[o * WLDS_STRIDE + seg * 8]) = v;
            }
        }
        __syncthreads();

        const int rec = (tap << 6) + (wave << 4) + lm;
        const int4   a4 = sA[rec];
        const float4 w4 = sWt[rec];

#pragma unroll
        for (int c0 = 0; c0 < CC; c0 += 32) {
            const int cb = (c0 + quad * 8) * 2;   // byte offset of this lane's 8 channels
            const uint4 v00 = *reinterpret_cast<const uint4*>(xb + a4.x + cb);
            const uint4 v01 = *reinterpret_cast<const uint4*>(xb + a4.y + cb);
            const uint4 v10 = *reinterpret_cast<const uint4*>(xb + a4.z + cb);
            const uint4 v11 = *reinterpret_cast<const uint4*>(xb + a4.w + cb);
            const unsigned* u00 = reinterpret_cast<const unsigned*>(&v00);
            const unsigned* u01 = reinterpret_cast<const unsigned*>(&v01);
            const unsigned* u10 = reinterpret_cast<const unsigned*>(&v10);
            const unsigned* u11 = reinterpret_cast<const unsigned*>(&v11);
            unsigned afu[4];
#pragma unroll
            for (int j = 0; j < 4; ++j) {
                const unsigned p00 = u00[j], p01 = u01[j], p10 = u10[j], p11 = u11[j];
                const float lo = w4.x * bf2f(p00 & 0xFFFFu) + w4.y * bf2f(p01 & 0xFFFFu)
                               + w4.z * bf2f(p10 & 0xFFFFu) + w4.w * bf2f(p11 & 0xFFFFu);
                const float hi = w4.x * bf2f(p00 >> 16) + w4.y * bf2f(p01 >> 16)
                               + w4.z * bf2f(p10 >> 16) + w4.w * bf2f(p11 >> 16);
                afu[j] = (unsigned)f2bf(lo) | ((unsigned)f2bf(hi) << 16);
            }
            const bf16x8 afrag = *reinterpret_cast<const bf16x8*>(afu);
#pragma unroll
            for (int nt = 0; nt < 8; ++nt) {
                const bf16x8 bfrag = *reinterpret_cast<const bf16x8*>(
                    &wlds[(nt * 16 + lm) * WLDS_STRIDE + c0 + quad * 8]);
                acc[nt] = __builtin_amdgcn_mfma_f32_16x16x32_bf16(afrag, bfrag, acc[nt], 0, 0, 0);
            }
        }
        __syncthreads();
    }

    // ---- epilogue: D lane map (verified m89): m=(lane>>4)*4+reg, n=lane&15 ----
    const int wo = (wave << 4) + quad * 4;
#pragma unroll
    for (int nt = 0; nt < 8; ++nt) {
        const int o = (nt << 4) + lm;
        const float bv = bias[o];
        float* op = out + ((((size_t)b * OO + o) * HH + ho) << 6) + wo;
        float4 v = {acc[nt][0] + bv, acc[nt][1] + bv, acc[nt][2] + bv, acc[nt][3] + bv};
        *reinterpret_cast<float4*>(op) = v;
    }
}

extern "C" void kernel_launch(void* const* d_in, const int* in_sizes, int n_in,
                              void* d_out, int out_size, void* d_ws, size_t ws_size,
                              hipStream_t stream) {
    const float* x      = (const float*)d_in[0];
    const float* offset = (const float*)d_in[1];
    const float* wgt    = (const float*)d_in[2];
    const float* bias   = (const float*)d_in[3];
    float* out = (float*)d_out;

    unsigned short* xt = (unsigned short*)d_ws;                       // 8 MiB
    unsigned short* wt = xt + (size_t)BB * HH * WW * CC;              // +288 KiB

    hipLaunchKernelGGL(transpose_w_kernel, dim3((OO * CC * KTAPS + 255) / 256), dim3(256),
                       0, stream, wgt, wt);
    hipLaunchKernelGGL(transpose_x_kernel, dim3(BB * HH), dim3(256), 0, stream, x, xt);
    hipLaunchKernelGGL(dcn_mfma_kernel, dim3(BB * HH), dim3(256), 0, stream,
                       xt, wt, offset, bias, out);
}